// Round 1
// baseline (432.879 us; speedup 1.0000x reference)
//
#include <hip/hip_runtime.h>
#include <math.h>

#define NB 32
#define CIN 32
#define DIM 32
#define KK 5
#define VALID 17
#define CVOL (VALID*VALID*VALID)   // 4913

// ws layout (floats): [0,4000) = w_eff ; [4000] = B ; [4096, 4096+32*4913) = C

__global__ __launch_bounds__(256) void prep_kernel(const float* __restrict__ weight,
                                                   const float* __restrict__ bias,
                                                   float* __restrict__ ws) {
    int idx = blockIdx.x * 256 + threadIdx.x;
    if (idx < 4000) {
        float s = 0.f;
        #pragma unroll 8
        for (int co = 0; co < 64; ++co) s += weight[co * 4000 + idx];
        ws[idx] = s;
    }
    if (idx == 0) {
        float b = 0.f;
        for (int i = 0; i < 64; ++i) b += bias[i];
        ws[4000] = b;
    }
}

// One block per (n, d-plane). Threads: 192 (3 waves); 153 active for compute:
// h = tid/9 in [0,17), wq = tid%9, each computes outputs w = 2*wq, 2*wq+1.
// LDS slab: [cin2][kd][ph 37][pw 40], ph = ih+2, pw = iw+2, zero-padded.
__global__ __launch_bounds__(192) void conv_kernel(const float* __restrict__ x,
                                                   const float* __restrict__ weff,
                                                   float* __restrict__ C) {
    __shared__ __align__(16) float slab[2][5][37][40];  // 59200 B
    const int b = blockIdx.x;
    const int n = b / VALID;
    const int d = b % VALID;
    const int tid = threadIdx.x;

    // zero-fill (OOB pattern is identical across cin chunks; pads never rewritten)
    float4* s4 = (float4*)slab;
    for (int t = tid; t < (2*5*37*40)/4; t += 192) s4[t] = make_float4(0.f,0.f,0.f,0.f);

    const bool active = tid < 153;
    const int h  = tid / 9;
    const int wq = tid - 9 * (tid / 9);
    float acc0 = 0.f, acc1 = 0.f;

    __syncthreads();

    for (int cc = 0; cc < 16; ++cc) {
        // load 2 cin planes: 2*5*32*32 floats as float2 granules (coalesced)
        for (int g = tid; g < 5120; g += 192) {
            int c2 = g / 2560;
            int r  = g - c2 * 2560;
            int kd = r / 512;
            int r2 = r - kd * 512;
            int ih = r2 >> 4;
            int iw = (r2 & 15) * 2;
            int id = 2 * d - 2 + kd;
            if (id >= 0 && id < DIM) {
                const float2 v = *(const float2*)&x[((((size_t)n * CIN + (2*cc + c2)) * DIM + id) * DIM + ih) * DIM + iw];
                *(float2*)&slab[c2][kd][ih + 2][iw + 2] = v;
            }
        }
        __syncthreads();

        if (active) {
            #pragma unroll
            for (int c2 = 0; c2 < 2; ++c2) {
                const float* wb = weff + (2*cc + c2) * 125;   // wave-uniform -> s_load
                #pragma unroll
                for (int kd = 0; kd < KK; ++kd) {
                    #pragma unroll
                    for (int kh = 0; kh < KK; ++kh) {
                        const float w0 = wb[(kd*5+kh)*5 + 0];
                        const float w1 = wb[(kd*5+kh)*5 + 1];
                        const float w2 = wb[(kd*5+kh)*5 + 2];
                        const float w3 = wb[(kd*5+kh)*5 + 3];
                        const float w4 = wb[(kd*5+kh)*5 + 4];
                        const float4* rowp = (const float4*)&slab[c2][kd][2*h + kh][0];
                        float4 va = rowp[wq];
                        float4 vb = rowp[wq + 1];
                        acc0 += w0*va.x + w1*va.y + w2*va.z + w3*va.w + w4*vb.x;
                        acc1 += w0*va.z + w1*va.w + w2*vb.x + w3*vb.y + w4*vb.z;
                    }
                }
            }
        }
        __syncthreads();
    }

    if (active) {
        float* Cn = C + ((size_t)(n * VALID + d) * VALID + h) * VALID;
        int w0 = 2 * wq;
        Cn[w0] = acc0;
        if (w0 + 1 < VALID) Cn[w0 + 1] = acc1;
    }
}

// One thread per output element [32][10][10][10].
__global__ __launch_bounds__(256) void pool_kernel(const float* __restrict__ C,
                                                   const float* __restrict__ wsB,
                                                   float* __restrict__ out) {
    int idx = blockIdx.x * 256 + threadIdx.x;
    if (idx >= 32000) return;
    int n = idx / 1000;
    int r = idx - n * 1000;
    int i = r / 100;
    int r2 = r - i * 100;
    int j = r2 / 10;
    int k = r2 - j * 10;

    float B = wsB[0];
    float result;
    if (i < 3 && j < 3 && k < 3) {
        const float* Cn = C + (size_t)n * CVOL;
        result = 0.f;
        for (int a = 3*i; a < 3*i + 3; ++a)
            for (int bb = 3*j; bb < 3*j + 3; ++bb)
                for (int c = 3*k; c < 3*k + 3; ++c) {
                    float m = -INFINITY;
                    #pragma unroll
                    for (int dd = 0; dd < 2; ++dd)
                        #pragma unroll
                        for (int dh = 0; dh < 2; ++dh)
                            #pragma unroll
                            for (int dw = 0; dw < 2; ++dw) {
                                int dz = 2*a + dd, hz = 2*bb + dh, wz = 2*c + dw;
                                float v = (dz < VALID && hz < VALID && wz < VALID)
                                          ? (Cn[(dz*VALID + hz)*VALID + wz] + B) : B;
                                m = fmaxf(m, v);
                            }
                    result += m;
                }
    } else {
        result = 27.f * B;
    }
    out[idx] = result;
}

extern "C" void kernel_launch(void* const* d_in, const int* in_sizes, int n_in,
                              void* d_out, int out_size, void* d_ws, size_t ws_size,
                              hipStream_t stream) {
    const float* x      = (const float*)d_in[0];
    const float* weight = (const float*)d_in[1];
    const float* bias   = (const float*)d_in[2];
    float* out = (float*)d_out;
    float* ws  = (float*)d_ws;
    float* weff = ws;
    float* wsB  = ws + 4000;
    float* C    = ws + 4096;

    hipLaunchKernelGGL(prep_kernel, dim3(16), dim3(256), 0, stream, weight, bias, ws);
    hipLaunchKernelGGL(conv_kernel, dim3(NB * VALID), dim3(192), 0, stream, x, weff, C);
    hipLaunchKernelGGL(pool_kernel, dim3(125), dim3(256), 0, stream, C, wsB, out);
}

// Round 3
// 218.911 us; speedup vs baseline: 1.9774x; 1.9774x over previous
//
#include <hip/hip_runtime.h>
#include <math.h>

#define NB 32
#define CIN 32
#define DIM 32
#define KK 5
#define VALID 17
#define CVOL (VALID*VALID*VALID)   // 4913
#define RS 44                      // slab row stride (words): 4-way max conflict, float4-aligned

// ws layout (floats): [0,4000) = w_eff ; [4000] = B ; [4096, ...) = C partials [nsplit][32][4913]

__global__ __launch_bounds__(256) void prep_kernel(const float* __restrict__ weight,
                                                   const float* __restrict__ bias,
                                                   float* __restrict__ ws) {
    int idx = blockIdx.x * 256 + threadIdx.x;
    if (idx < 4000) {
        float s = 0.f;
        #pragma unroll 8
        for (int co = 0; co < 64; ++co) s += weight[co * 4000 + idx];
        ws[idx] = s;
    }
    if (idx == 0) {
        float b = 0.f;
        for (int i = 0; i < 64; ++i) b += bias[i];
        ws[4000] = b;
    }
}

// Block = (split s, n, d). 192 threads (3 waves); 153 active for compute:
// h = tid/9 in [0,17), wq = tid%9 -> outputs w = 2wq, 2wq+1.
// LDS slab: one cin at a time, [kd 5][ph 37][RS 44], input at pw = iw+2.
__global__ __launch_bounds__(192) void conv_kernel(const float* __restrict__ x,
                                                   const float* __restrict__ weff,
                                                   float* __restrict__ C,
                                                   int cpS) {   // cins per split
    __shared__ __align__(16) float slab[KK][37][RS];   // 32560 B -> 5 blocks/CU
    const int b = blockIdx.x;
    const int s = b / (NB * VALID);
    const int rem = b - s * (NB * VALID);
    const int n = rem / VALID;
    const int d = rem - n * VALID;
    const int tid = threadIdx.x;

    // zero-fill once: pads + OOB kd planes are never rewritten
    float4* s4 = (float4*)slab;
    for (int t = tid; t < (KK*37*RS)/4; t += 192) s4[t] = make_float4(0.f,0.f,0.f,0.f);

    const bool active = tid < 153;
    const int h  = tid / 9;
    const int wq = tid - 9 * (tid / 9);
    float acc0a = 0.f, acc0b = 0.f, acc1a = 0.f, acc1b = 0.f;

    __syncthreads();

    const int cin0 = s * cpS;
    for (int ci = 0; ci < cpS; ++ci) {
        const int cin = cin0 + ci;
        // load one cin: 5 kd-planes of 32x32, as float4 from global (coalesced),
        // stored as 2x float2 (dest word 2+4*iw4 is 8B-aligned).
        for (int g = tid; g < 1280; g += 192) {
            int kd = g >> 8;
            int r  = g & 255;
            int ih = r >> 3;
            int iw4 = r & 7;
            int id = 2 * d - 2 + kd;
            if (id >= 0 && id < DIM) {
                const float4 v = *(const float4*)&x[((((size_t)n * CIN + cin) * DIM + id) * DIM + ih) * DIM + 4*iw4];
                float* dst = &slab[kd][ih + 2][2 + 4*iw4];
                *(float2*)dst       = make_float2(v.x, v.y);
                *(float2*)(dst + 2) = make_float2(v.z, v.w);
            }
        }
        __syncthreads();

        if (active) {
            const float* wb = weff + cin * 125;   // wave-uniform -> scalar loads
            #pragma unroll
            for (int kd = 0; kd < KK; ++kd) {
                #pragma unroll
                for (int kh = 0; kh < KK; ++kh) {
                    const float w0 = wb[(kd*5+kh)*5 + 0];
                    const float w1 = wb[(kd*5+kh)*5 + 1];
                    const float w2 = wb[(kd*5+kh)*5 + 2];
                    const float w3 = wb[(kd*5+kh)*5 + 3];
                    const float w4 = wb[(kd*5+kh)*5 + 4];
                    const float4* rowp = (const float4*)&slab[kd][2*h + kh][0];
                    float4 va = rowp[wq];
                    float4 vb = rowp[wq + 1];
                    acc0a = fmaf(w0, va.x, acc0a);
                    acc0b = fmaf(w1, va.y, acc0b);
                    acc0a = fmaf(w2, va.z, acc0a);
                    acc0b = fmaf(w3, va.w, acc0b);
                    acc0a = fmaf(w4, vb.x, acc0a);
                    acc1a = fmaf(w0, va.z, acc1a);
                    acc1b = fmaf(w1, va.w, acc1b);
                    acc1a = fmaf(w2, vb.x, acc1a);
                    acc1b = fmaf(w3, vb.y, acc1b);
                    acc1a = fmaf(w4, vb.z, acc1a);
                }
            }
        }
        __syncthreads();
    }

    if (active) {
        float* Cn = C + ((size_t)s * NB + n) * CVOL + ((size_t)d * VALID + h) * VALID;
        int w0 = 2 * wq;
        Cn[w0] = acc0a + acc0b;
        if (w0 + 1 < VALID) Cn[w0 + 1] = acc1a + acc1b;
    }
}

// One thread per output element [32][10][10][10]; sums nsplit partial C buffers.
__global__ __launch_bounds__(256) void pool_kernel(const float* __restrict__ C,
                                                   const float* __restrict__ wsB,
                                                   float* __restrict__ out,
                                                   int nsplit) {
    int idx = blockIdx.x * 256 + threadIdx.x;
    if (idx >= 32000) return;
    int n = idx / 1000;
    int r = idx - n * 1000;
    int i = r / 100;
    int r2 = r - i * 100;
    int j = r2 / 10;
    int k = r2 - j * 10;

    float B = wsB[0];
    float result;
    if (i < 3 && j < 3 && k < 3) {
        result = 0.f;
        for (int a = 3*i; a < 3*i + 3; ++a)
            for (int bb = 3*j; bb < 3*j + 3; ++bb)
                for (int c = 3*k; c < 3*k + 3; ++c) {
                    float m = -INFINITY;
                    #pragma unroll
                    for (int dd = 0; dd < 2; ++dd)
                        #pragma unroll
                        for (int dh = 0; dh < 2; ++dh)
                            #pragma unroll
                            for (int dw = 0; dw < 2; ++dw) {
                                int dz = 2*a + dd, hz = 2*bb + dh, wz = 2*c + dw;
                                float v;
                                if (dz < VALID && hz < VALID && wz < VALID) {
                                    size_t o = (size_t)n * CVOL + ((size_t)dz * VALID + hz) * VALID + wz;
                                    float sum = 0.f;
                                    for (int ss = 0; ss < nsplit; ++ss)
                                        sum += C[(size_t)ss * NB * CVOL + o];
                                    v = sum + B;
                                } else {
                                    v = B;
                                }
                                m = fmaxf(m, v);
                            }
                    result += m;
                }
    } else {
        result = 27.f * B;
    }
    out[idx] = result;
}

extern "C" void kernel_launch(void* const* d_in, const int* in_sizes, int n_in,
                              void* d_out, int out_size, void* d_ws, size_t ws_size,
                              hipStream_t stream) {
    const float* x      = (const float*)d_in[0];
    const float* weight = (const float*)d_in[1];
    const float* bias   = (const float*)d_in[2];
    float* out = (float*)d_out;
    float* ws  = (float*)d_ws;
    float* weff = ws;
    float* wsB  = ws + 4000;
    float* C    = ws + 4096;

    // pick cin-split by available workspace
    int nsplit = 1;
    if (ws_size >= (size_t)(4096 + 4 * NB * CVOL) * 4) nsplit = 4;
    else if (ws_size >= (size_t)(4096 + 2 * NB * CVOL) * 4) nsplit = 2;
    int cpS = CIN / nsplit;

    prep_kernel<<<dim3(16), dim3(256), 0, stream>>>(weight, bias, ws);
    conv_kernel<<<dim3(nsplit * NB * VALID), dim3(192), 0, stream>>>(x, weff, C, cpS);
    pool_kernel<<<dim3(125), dim3(256), 0, stream>>>(C, wsB, out, nsplit);
}